// Round 9
// baseline (1365.539 us; speedup 1.0000x reference)
//
#include <hip/hip_runtime.h>

#define Bq 8
#define Nq 8192
#define NPOINT 1024
#define NSAMPLE 32
#define DF 64
#define RAD2 0.0625f
#define FPS_T 1024
#define FPS_PPT (Nq / FPS_T) /* 8 */
#define FPS_PAIRS (FPS_PPT / 2)

typedef float v2f __attribute__((ext_vector_type(2)));

// DPP neighbor-combine steps on the VALU pipe. GCNDPPCombine fuses the
// mov_dpp into the consuming max/min (v_max_f32_dpp / v_min_u32_dpp).
#define DPPF_MAX(v, CTRL)                                                     \
    {                                                                         \
        const float nv = __int_as_float(__builtin_amdgcn_update_dpp(          \
            __float_as_int(v), __float_as_int(v), CTRL, 0xf, 0xf, false));    \
        v = fmaxf(v, nv);                                                     \
    }
#define DPPU_MIN(ci, CTRL)                                                    \
    {                                                                         \
        const unsigned nci = (unsigned)__builtin_amdgcn_update_dpp(           \
            (int)ci, (int)ci, CTRL, 0xf, 0xf, false);                         \
        ci = (nci < ci) ? nci : ci;                                           \
    }
#define DPPMOVF(dst, src, CTRL)                                               \
    const float dst = __int_as_float(__builtin_amdgcn_update_dpp(             \
        __float_as_int(src), __float_as_int(src), CTRL, 0xf, 0xf, false));
#define DPPMOVU(dst, src, CTRL)                                               \
    const unsigned dst = (unsigned)__builtin_amdgcn_update_dpp(               \
        (int)src, (int)src, CTRL, 0xf, 0xf, false);

// ---------------------------------------------------------------------------
// Kernel 1: FPS, one block (1024 thr, 16 waves) per batch.
// Points in REGISTERS (packed v2f pairs -> v_pk_*_f32), no LDS in hot loop.
// One barrier/iter. Reduce = split (f32 value-max, u32 index-min) DPP steps:
// row butterfly (xor1,xor2,half_mirror,mirror) then bcast15/31 collapse,
// candidate index masked by value-equality at each stage -> (max d, tie min
// index), bit-identical selection to the u64-packed version.
// Bit-exact: d = ((dx*dx)+(dy*dy))+(dz*dz) plain chain (contract off), fminf,
// first-occurrence argmax: strict > over ascending per-thread indices.
// ---------------------------------------------------------------------------
__global__ void __launch_bounds__(FPS_T, 1)
fps_kernel(const float* __restrict__ xyz, float* __restrict__ new_xyz)
{
#pragma clang fp contract(off)
    extern __shared__ float lds[];
    float4* tab = (float4*)lds;                     // 8192 * 16B = 128 KB
    __shared__ float    wv[2][64];                  // [parity][wave*4+row]
    __shared__ unsigned wi[2][64];

    const int b    = blockIdx.x;
    const int t    = threadIdx.x;
    const int lane = t & 63;
    const int wid  = t >> 6;
    const float* xb = xyz + (size_t)b * Nq * 3;

    v2f px[FPS_PAIRS], py[FPS_PAIRS], pz[FPS_PAIRS], dist[FPS_PAIRS];
    int i0c[FPS_PAIRS], i1c[FPS_PAIRS];
#pragma unroll
    for (int k = 0; k < FPS_PAIRS; ++k) {
        const int i0 = t + (2 * k + 0) * FPS_T;
        const int i1 = t + (2 * k + 1) * FPS_T;
        i0c[k] = i0; i1c[k] = i1;
        const float x0 = xb[i0 * 3 + 0], y0 = xb[i0 * 3 + 1], z0 = xb[i0 * 3 + 2];
        const float x1 = xb[i1 * 3 + 0], y1 = xb[i1 * 3 + 1], z1 = xb[i1 * 3 + 2];
        px[k] = (v2f){x0, x1}; py[k] = (v2f){y0, y1}; pz[k] = (v2f){z0, z1};
        dist[k] = (v2f){1e10f, 1e10f};
        tab[i0] = make_float4(x0, y0, z0, 0.0f);
        tab[i1] = make_float4(x1, y1, z1, 0.0f);
    }
    __syncthreads();

    float4 c = tab[0];                              // centroid 0 = point 0
    float* ob = new_xyz + (size_t)b * NPOINT * 3;

    for (int it = 0; it < NPOINT; ++it) {
        if (t == 0) {
            ob[it * 3 + 0] = c.x;
            ob[it * 3 + 1] = c.y;
            ob[it * 3 + 2] = c.z;
        }
        const v2f cx2 = (v2f){c.x, c.x};
        const v2f cy2 = (v2f){c.y, c.y};
        const v2f cz2 = (v2f){c.z, c.z};
        float bv = -1.0f;
        int   bi = Nq;
#pragma unroll
        for (int k = 0; k < FPS_PAIRS; ++k) {
            const v2f dx = px[k] - cx2;             // v_pk_add (neg)
            const v2f dy = py[k] - cy2;
            const v2f dz = pz[k] - cz2;
            const v2f sx = dx * dx;                 // v_pk_mul
            const v2f sy = dy * dy;
            const v2f sz = dz * dz;
            const v2f d  = (sx + sy) + sz;          // v_pk_add, L-to-R chain
            const v2f nd = __builtin_elementwise_min(dist[k], d);
            dist[k] = nd;
            if (nd.x > bv) { bv = nd.x; bi = i0c[k]; }   // strict >, asc idx
            if (nd.y > bv) { bv = nd.y; bi = i1c[k]; }
        }
        // in-wave row reduce: value max, then index min among value-ties
        float v = bv;
        DPPF_MAX(v, 0xB1) DPPF_MAX(v, 0x4E)
        DPPF_MAX(v, 0x141) DPPF_MAX(v, 0x140)
        unsigned ci = (bv == v) ? (unsigned)bi : 0xffffffffu;
        DPPU_MIN(ci, 0xB1) DPPU_MIN(ci, 0x4E)
        DPPU_MIN(ci, 0x141) DPPU_MIN(ci, 0x140)
        const int p = it & 1;
        if ((lane & 15) == 0) {
            const int e = wid * 4 + (lane >> 4);
            wv[p][e] = v;
            wi[p][e] = ci;
        }
        __syncthreads();
        // cross-wave: 64 entries -> row reduce -> bcast15/31 collapse
        const float    gv = wv[p][lane];
        const unsigned gi = wi[p][lane];
        float rv = gv;
        DPPF_MAX(rv, 0xB1) DPPF_MAX(rv, 0x4E)
        DPPF_MAX(rv, 0x141) DPPF_MAX(rv, 0x140)
        unsigned ci2 = (gv == rv) ? gi : 0xffffffffu;
        DPPU_MIN(ci2, 0xB1) DPPU_MIN(ci2, 0x4E)
        DPPU_MIN(ci2, 0x141) DPPU_MIN(ci2, 0x140)
        // bcast15: row0->row1, row2->row3 (rows 0,2 keep old)
        DPPMOVF(rvb, rv, 0x142)
        const float rv2 = fmaxf(rv, rvb);
        DPPMOVU(cib, ci2, 0x142)
        const unsigned cA = (rv  == rv2) ? ci2 : 0xffffffffu;
        const unsigned cB = (rvb == rv2) ? cib : 0xffffffffu;
        const unsigned ci3 = (cA < cB) ? cA : cB;
        // bcast31: rows 0-1 -> rows 2,3
        DPPMOVF(rvc, rv2, 0x143)
        const float rv3 = fmaxf(rv2, rvc);
        DPPMOVU(cic, ci3, 0x143)
        const unsigned cC = (rv2 == rv3) ? ci3 : 0xffffffffu;
        const unsigned cD = (rvc == rv3) ? cic : 0xffffffffu;
        const unsigned ci4 = (cC < cD) ? cC : cD;
        const int far = __builtin_amdgcn_readlane((int)ci4, 63);
        c = tab[far];                               // uniform addr broadcast
    }
}

// ---------------------------------------------------------------------------
// Kernel 2: ball query, one wave per query (unchanged, verified absmax 0).
// ---------------------------------------------------------------------------
__global__ void __launch_bounds__(256, 4)
ballq_kernel(const float* __restrict__ xyz, const float* __restrict__ new_xyz,
             int* __restrict__ ball_idx)
{
#pragma clang fp contract(off)
    __shared__ int sel[4][NSAMPLE];
    const int w    = threadIdx.x >> 6;
    const int lane = threadIdx.x & 63;
    const int wq   = blockIdx.x * 4 + w;
    const int b    = wq >> 10;

    const float qx = new_xyz[wq * 3 + 0];
    const float qy = new_xyz[wq * 3 + 1];
    const float qz = new_xyz[wq * 3 + 2];
    const float ssrc = qx * qx + qy * qy + qz * qz;   // plain chain
    const float* xb = xyz + (size_t)b * Nq * 3;

    int cnt = 0;
    for (int base = 0; base < Nq; base += 64) {
        const int i = base + lane;
        const float px = xb[i * 3 + 0];
        const float py = xb[i * 3 + 1];
        const float pz = xb[i * 3 + 2];
        const float dot  = __builtin_fmaf(pz, qz, __builtin_fmaf(py, qy, px * qx));
        const float sdst = px * px + py * py + pz * pz;           // plain chain
        const float d    = (-2.0f * dot + ssrc) + sdst;
        const bool  in   = (d <= RAD2);
        const unsigned long long m = __ballot(in);
        if (in) {
            const int slot = cnt + (int)__popcll(m & ((1ull << lane) - 1ull));
            if (slot < NSAMPLE) sel[w][slot] = i;
        }
        cnt += (int)__popcll(m);
        if (cnt >= NSAMPLE) break;
    }
    const int first = sel[w][0];
    if (cnt < NSAMPLE) {
        for (int s = cnt + lane; s < NSAMPLE; s += 64) sel[w][s] = first;
    }
    if (lane < NSAMPLE) ball_idx[(size_t)wq * NSAMPLE + lane] = sel[w][lane];
}

// ---------------------------------------------------------------------------
// Kernel 3: gather + concat (unchanged, verified absmax 0).
// ---------------------------------------------------------------------------
__global__ void __launch_bounds__(256)
fill_kernel(const float* __restrict__ xyz, const float* __restrict__ points,
            const float* __restrict__ new_xyz, const int* __restrict__ ball_idx,
            float* __restrict__ new_points)
{
#pragma clang fp contract(off)
    const int TOT = Bq * NPOINT * NSAMPLE * (3 + DF);
    const int t = blockIdx.x * 256 + threadIdx.x;
    if (t >= TOT) return;
    const int c  = t % (3 + DF);
    const int g  = t / (3 + DF);
    const int bq = g >> 5;
    const int b  = bq >> 10;
    const int idx = ball_idx[g];
    float v;
    if (c < 3) {
        v = xyz[((size_t)b * Nq + idx) * 3 + c] - new_xyz[(size_t)bq * 3 + c];
    } else {
        v = points[((size_t)b * Nq + idx) * DF + (c - 3)];
    }
    new_points[t] = v;
}

// ---------------------------------------------------------------------------
extern "C" void kernel_launch(void* const* d_in, const int* in_sizes, int n_in,
                              void* d_out, int out_size, void* d_ws, size_t ws_size,
                              hipStream_t stream)
{
    (void)in_sizes; (void)n_in; (void)out_size; (void)ws_size;
    const float* xyz    = (const float*)d_in[0];
    const float* points = (const float*)d_in[1];
    float* out        = (float*)d_out;
    float* new_xyz    = out;                               // Bq*NPOINT*3
    float* new_points = out + (size_t)Bq * NPOINT * 3;     // rest
    int*   ball_idx   = (int*)d_ws;                        // Bq*NPOINT*NSAMPLE

    hipFuncSetAttribute(reinterpret_cast<const void*>(fps_kernel),
                        hipFuncAttributeMaxDynamicSharedMemorySize,
                        Nq * (int)sizeof(float4));

    fps_kernel<<<Bq, FPS_T, Nq * sizeof(float4), stream>>>(xyz, new_xyz);
    ballq_kernel<<<(Bq * NPOINT) / 4, 256, 0, stream>>>(xyz, new_xyz, ball_idx);
    const int TOT = Bq * NPOINT * NSAMPLE * (3 + DF);
    fill_kernel<<<(TOT + 255) / 256, 256, 0, stream>>>(xyz, points, new_xyz,
                                                       ball_idx, new_points);
}

// Round 10
// 1278.626 us; speedup vs baseline: 1.0680x; 1.0680x over previous
//
#include <hip/hip_runtime.h>

#define Bq 8
#define Nq 8192
#define NPOINT 1024
#define NSAMPLE 32
#define DF 64
#define RAD2 0.0625f
#define FPS_T 1024
#define FPS_PPT (Nq / FPS_T) /* 8 */
#define FPS_PAIRS (FPS_PPT / 2)

typedef float v2f __attribute__((ext_vector_type(2)));

// One u64-max DPP step: combine with lane given by dpp_ctrl (VALU pipe).
#define DPP_STEP_U64(k, CTRL)                                                 \
    {                                                                         \
        unsigned int lo = (unsigned int)k, hi = (unsigned int)(k >> 32);      \
        unsigned int nlo = (unsigned int)__builtin_amdgcn_update_dpp(         \
            (int)lo, (int)lo, CTRL, 0xf, 0xf, false);                         \
        unsigned int nhi = (unsigned int)__builtin_amdgcn_update_dpp(         \
            (int)hi, (int)hi, CTRL, 0xf, 0xf, false);                         \
        unsigned long long nk = ((unsigned long long)nhi << 32) | nlo;        \
        if (nk > k) k = nk;                                                   \
    }

// 16-lane-row butterfly max: xor1 (0xB1), xor2 (0x4E), half_mirror (0x141),
// mirror (0x140). Every lane ends with its row's max.
__device__ __forceinline__ unsigned long long rowmax16(unsigned long long k)
{
    DPP_STEP_U64(k, 0xB1) DPP_STEP_U64(k, 0x4E)
    DPP_STEP_U64(k, 0x141) DPP_STEP_U64(k, 0x140)
    return k;
}

__device__ __forceinline__ unsigned long long readlane_u64(unsigned long long k, int l)
{
    const unsigned int lo = (unsigned int)__builtin_amdgcn_readlane((int)(unsigned int)k, l);
    const unsigned int hi = (unsigned int)__builtin_amdgcn_readlane((int)(unsigned int)(k >> 32), l);
    return ((unsigned long long)hi << 32) | lo;
}

// ---------------------------------------------------------------------------
// Kernel 1: FPS, one block (1024 thr, 16 waves) per batch.
// Points in REGISTERS (packed v2f pairs -> v_pk_*_f32), no LDS in hot loop.
// One barrier/iter. Reduce: rowmax16 -> 4 row leaders/wave write (64 LDS
// entries) -> every wave reads wbest[lane], rowmax16 + row_bcast15/31
// collapse (rows 0,2 keep old via old-operand; max stays correct) ->
// readlane(63). All cross-lane traffic on the VALU DPP pipe.
// Bit-exact: d = ((dx*dx)+(dy*dy))+(dz*dz) plain chain (contract off), fminf,
// first-occurrence argmax: strict > over ascending per-thread indices, then
// commutative max over packed u64 (d_bits<<32 | ~i) == (max d, tie min i).
// ---------------------------------------------------------------------------
__global__ void __launch_bounds__(FPS_T, 1)
fps_kernel(const float* __restrict__ xyz, float* __restrict__ new_xyz)
{
#pragma clang fp contract(off)
    extern __shared__ float lds[];
    float4* tab = (float4*)lds;                     // 8192 * 16B = 128 KB
    __shared__ unsigned long long wbest[2][64];     // [parity][wave*4+row]

    const int b    = blockIdx.x;
    const int t    = threadIdx.x;
    const int lane = t & 63;
    const int wid  = t >> 6;
    const float* xb = xyz + (size_t)b * Nq * 3;

    v2f px[FPS_PAIRS], py[FPS_PAIRS], pz[FPS_PAIRS], dist[FPS_PAIRS];
    int i0c[FPS_PAIRS], i1c[FPS_PAIRS];             // hoisted index constants
#pragma unroll
    for (int k = 0; k < FPS_PAIRS; ++k) {
        const int i0 = t + (2 * k + 0) * FPS_T;
        const int i1 = t + (2 * k + 1) * FPS_T;
        i0c[k] = i0; i1c[k] = i1;
        const float x0 = xb[i0 * 3 + 0], y0 = xb[i0 * 3 + 1], z0 = xb[i0 * 3 + 2];
        const float x1 = xb[i1 * 3 + 0], y1 = xb[i1 * 3 + 1], z1 = xb[i1 * 3 + 2];
        px[k] = (v2f){x0, x1}; py[k] = (v2f){y0, y1}; pz[k] = (v2f){z0, z1};
        dist[k] = (v2f){1e10f, 1e10f};
        tab[i0] = make_float4(x0, y0, z0, 0.0f);
        tab[i1] = make_float4(x1, y1, z1, 0.0f);
    }
    __syncthreads();

    float4 c = tab[0];                              // centroid 0 = point 0
    float* ob = new_xyz + (size_t)b * NPOINT * 3;

    for (int it = 0; it < NPOINT; ++it) {
        if (t == 0) {
            ob[it * 3 + 0] = c.x;
            ob[it * 3 + 1] = c.y;
            ob[it * 3 + 2] = c.z;
        }
        const v2f cx2 = (v2f){c.x, c.x};
        const v2f cy2 = (v2f){c.y, c.y};
        const v2f cz2 = (v2f){c.z, c.z};
        float bv = -1.0f;
        int   bi = Nq;
#pragma unroll
        for (int k = 0; k < FPS_PAIRS; ++k) {
            const v2f dx = px[k] - cx2;             // v_pk_add (neg)
            const v2f dy = py[k] - cy2;
            const v2f dz = pz[k] - cz2;
            const v2f sx = dx * dx;                 // v_pk_mul
            const v2f sy = dy * dy;
            const v2f sz = dz * dz;
            const v2f d  = (sx + sy) + sz;          // v_pk_add, L-to-R chain
            const v2f nd = __builtin_elementwise_min(dist[k], d);
            dist[k] = nd;
            if (nd.x > bv) { bv = nd.x; bi = i0c[k]; }   // strict >, asc idx
            if (nd.y > bv) { bv = nd.y; bi = i1c[k]; }
        }
        // pack (value, ~index): u64 max == (max value, tie -> min index)
        unsigned long long k64 =
            ((unsigned long long)__float_as_uint(bv) << 32) |
            (unsigned int)(~bi);
        // wave: row butterfly; 4 row leaders write their row max
        k64 = rowmax16(k64);
        if ((lane & 15) == 0) wbest[it & 1][wid * 4 + (lane >> 4)] = k64;
        __syncthreads();
        // cross-wave: 64 entries, rowmax16 + bcast15/31 collapse -> lane 63
        unsigned long long g = wbest[it & 1][lane];
        g = rowmax16(g);
        DPP_STEP_U64(g, 0x142)                      // row_bcast15: r0->r1, r2->r3
        DPP_STEP_U64(g, 0x143)                      // row_bcast31: r1->r2,r3
        g = readlane_u64(g, 63);
        const int far = (int)(~(unsigned int)(g & 0xffffffffull));
        c = tab[far];                               // uniform addr broadcast
    }
}

// ---------------------------------------------------------------------------
// Kernel 2: ball query, one wave per query (unchanged, verified absmax 0).
// ---------------------------------------------------------------------------
__global__ void __launch_bounds__(256, 4)
ballq_kernel(const float* __restrict__ xyz, const float* __restrict__ new_xyz,
             int* __restrict__ ball_idx)
{
#pragma clang fp contract(off)
    __shared__ int sel[4][NSAMPLE];
    const int w    = threadIdx.x >> 6;
    const int lane = threadIdx.x & 63;
    const int wq   = blockIdx.x * 4 + w;
    const int b    = wq >> 10;

    const float qx = new_xyz[wq * 3 + 0];
    const float qy = new_xyz[wq * 3 + 1];
    const float qz = new_xyz[wq * 3 + 2];
    const float ssrc = qx * qx + qy * qy + qz * qz;   // plain chain
    const float* xb = xyz + (size_t)b * Nq * 3;

    int cnt = 0;
    for (int base = 0; base < Nq; base += 64) {
        const int i = base + lane;
        const float px = xb[i * 3 + 0];
        const float py = xb[i * 3 + 1];
        const float pz = xb[i * 3 + 2];
        const float dot  = __builtin_fmaf(pz, qz, __builtin_fmaf(py, qy, px * qx));
        const float sdst = px * px + py * py + pz * pz;           // plain chain
        const float d    = (-2.0f * dot + ssrc) + sdst;
        const bool  in   = (d <= RAD2);
        const unsigned long long m = __ballot(in);
        if (in) {
            const int slot = cnt + (int)__popcll(m & ((1ull << lane) - 1ull));
            if (slot < NSAMPLE) sel[w][slot] = i;
        }
        cnt += (int)__popcll(m);
        if (cnt >= NSAMPLE) break;
    }
    const int first = sel[w][0];
    if (cnt < NSAMPLE) {
        for (int s = cnt + lane; s < NSAMPLE; s += 64) sel[w][s] = first;
    }
    if (lane < NSAMPLE) ball_idx[(size_t)wq * NSAMPLE + lane] = sel[w][lane];
}

// ---------------------------------------------------------------------------
// Kernel 3: gather + concat (unchanged, verified absmax 0).
// ---------------------------------------------------------------------------
__global__ void __launch_bounds__(256)
fill_kernel(const float* __restrict__ xyz, const float* __restrict__ points,
            const float* __restrict__ new_xyz, const int* __restrict__ ball_idx,
            float* __restrict__ new_points)
{
#pragma clang fp contract(off)
    const int TOT = Bq * NPOINT * NSAMPLE * (3 + DF);
    const int t = blockIdx.x * 256 + threadIdx.x;
    if (t >= TOT) return;
    const int c  = t % (3 + DF);
    const int g  = t / (3 + DF);
    const int bq = g >> 5;
    const int b  = bq >> 10;
    const int idx = ball_idx[g];
    float v;
    if (c < 3) {
        v = xyz[((size_t)b * Nq + idx) * 3 + c] - new_xyz[(size_t)bq * 3 + c];
    } else {
        v = points[((size_t)b * Nq + idx) * DF + (c - 3)];
    }
    new_points[t] = v;
}

// ---------------------------------------------------------------------------
extern "C" void kernel_launch(void* const* d_in, const int* in_sizes, int n_in,
                              void* d_out, int out_size, void* d_ws, size_t ws_size,
                              hipStream_t stream)
{
    (void)in_sizes; (void)n_in; (void)out_size; (void)ws_size;
    const float* xyz    = (const float*)d_in[0];
    const float* points = (const float*)d_in[1];
    float* out        = (float*)d_out;
    float* new_xyz    = out;                               // Bq*NPOINT*3
    float* new_points = out + (size_t)Bq * NPOINT * 3;     // rest
    int*   ball_idx   = (int*)d_ws;                        // Bq*NPOINT*NSAMPLE

    hipFuncSetAttribute(reinterpret_cast<const void*>(fps_kernel),
                        hipFuncAttributeMaxDynamicSharedMemorySize,
                        Nq * (int)sizeof(float4));

    fps_kernel<<<Bq, FPS_T, Nq * sizeof(float4), stream>>>(xyz, new_xyz);
    ballq_kernel<<<(Bq * NPOINT) / 4, 256, 0, stream>>>(xyz, new_xyz, ball_idx);
    const int TOT = Bq * NPOINT * NSAMPLE * (3 + DF);
    fill_kernel<<<(TOT + 255) / 256, 256, 0, stream>>>(xyz, points, new_xyz,
                                                       ball_idx, new_points);
}